// Round 11
// baseline (407.304 us; speedup 1.0000x reference)
//
#include <hip/hip_runtime.h>

#define NN 100000
#define NE 1600000
#define NG 1024
#define NBLK_SCAN ((NN + 255) / 256)  // 391
#define CPAD 4

// merged-setup grid: even blocks = count (atomic-stalled, idle pipes),
// odd blocks = compute (Z-gemm/cvt/bounds/prep) -> co-scheduled per CU.
#define GB_COUNT 6250   // NE/256
#define GB_Z     1563
#define GB_CVT   3125
#define GB_BND   5
#define GB_PREP  320
#define GB_SETUP (2 * GB_COUNT)

// prep0 grid: 32 blocks pack pLZ, 1563 blocks zero cnt (+block 32 zeros desc)
#define GB_P0 (32 + (NN * CPAD + 255) / 256)

typedef __attribute__((ext_vector_type(8))) short bf16x8;
typedef __attribute__((ext_vector_type(4))) float f32x4;

__device__ __forceinline__ unsigned f2bf1(float f) {
  union { float f; unsigned u; } v; v.f = f;
  return (v.u + 0x7fffu + ((v.u >> 16) & 1u)) >> 16;  // RNE
}
__device__ __forceinline__ unsigned packbf2(float a, float b) {
  return f2bf1(a) | (f2bf1(b) << 16);
}
__device__ __forceinline__ float bflo(unsigned u) {
  union { unsigned u; float f; } v; v.u = u << 16; return v.f;
}
__device__ __forceinline__ float bfhi(unsigned u) {
  union { unsigned u; float f; } v; v.u = u & 0xffff0000u; return v.f;
}
__device__ __forceinline__ float bfs(unsigned short s) {
  union { unsigned u; float f; } v; v.u = ((unsigned)s) << 16; return v.f;
}

// -------- prep0: pack c1_wr B-frags + zero cnt + zero scan descriptors ------
__global__ __launch_bounds__(256) void k_prep0(const float* __restrict__ c1wr,
                                               unsigned short* __restrict__ pLZ,
                                               int* __restrict__ cnt,
                                               unsigned long long* __restrict__ desc) {
  int b = blockIdx.x, tid = threadIdx.x;
  if (b < 32) {
    int e = b * 256 + tid;  // 64*128 = 8192
    if (e < 64 * 128) {
      int k = e >> 7, n = e & 127;
      int t = k >> 5, kq = (k >> 3) & 3, j = k & 7;
      int n0 = n >> 4, nl = n & 15;
      pLZ[((((n0 * 2 + t) * 64) + (kq * 16 + nl)) << 3) + j] =
          (unsigned short)f2bf1(c1wr[k * 128 + n]);
    }
    return;
  }
  if (b == 32) { desc[tid] = 0ULL; desc[tid + 256] = 0ULL; }
  int i = (b - 32) * 256 + tid;
  if (i < NN * CPAD) cnt[i] = 0;
}

// ---------------------------------------------------------- merged setup ----
__global__ __launch_bounds__(256) void k_setup(
    const int* __restrict__ dst, int* __restrict__ cnt, int* __restrict__ rank,
    const float* __restrict__ X, unsigned short* __restrict__ Xb,
    const int* __restrict__ batch, int* __restrict__ gstart,
    const unsigned short* __restrict__ pLZ, const float* __restrict__ c1bl,
    unsigned short* __restrict__ ZZ,
    const float* __restrict__ c1wl, const float* __restrict__ c1wr,
    const float* __restrict__ c2wl, const float* __restrict__ c2wr,
    const float* __restrict__ c3wl, const float* __restrict__ c3wr,
    const float* __restrict__ c4wl, const float* __restrict__ c4wr,
    unsigned short* __restrict__ pL1, unsigned short* __restrict__ pL2a,
    unsigned short* __restrict__ pL2b, unsigned short* __restrict__ pL3,
    unsigned short* __restrict__ pL4) {
  __shared__ __align__(16) char smem[64 * 66 * 4];
  int b = blockIdx.x, tid = threadIdx.x;

  if ((b & 1) == 0) {  // ---- count (atomic-bound; pipes idle)
    int e = (b >> 1) * 256 + tid;
    rank[e] = atomicAdd(&cnt[(size_t)dst[e] * CPAD], 1);
    return;
  }
  int ob = b >> 1;

  if (ob < GB_Z) {  // ---- Z-gemm: ZZ = x @ c1_wr + c1_bl  (bf16, no relu)
    unsigned short* sA = (unsigned short*)smem;
    float* sC = (float*)smem;
    const int m0 = ob * 64;
#pragma unroll
    for (int l = 0; l < 2; ++l) {
      int c = tid + l * 256;
      int m = c >> 3, k8 = c & 7;
      int row = m0 + m;
      uint4 o = make_uint4(0, 0, 0, 0);
      if (row < NN) {
        const float4* xp = (const float4*)(X + (size_t)row * 64 + k8 * 8);
        float4 p0 = xp[0], p1 = xp[1];
        o.x = packbf2(p0.x, p0.y); o.y = packbf2(p0.z, p0.w);
        o.z = packbf2(p1.x, p1.y); o.w = packbf2(p1.z, p1.w);
      }
      int wv = m >> 4, mr = m & 15, t = k8 >> 2, kq = k8 & 3;
      ((uint4*)sA)[(wv * 2 + t) * 64 + kq * 16 + mr] = o;
    }
    __syncthreads();
    const int w = tid >> 6, L = tid & 63;
    const bf16x8* Af = (const bf16x8*)sA;
    const bf16x8* Bf = (const bf16x8*)pLZ;
    f32x4 acc[8];
#pragma unroll
    for (int i = 0; i < 8; ++i)
#pragma unroll
      for (int j = 0; j < 4; ++j) acc[i][j] = 0.f;
#pragma unroll
    for (int t = 0; t < 2; ++t) {
      bf16x8 afr = Af[(w * 2 + t) * 64 + L];
#pragma unroll
      for (int n0 = 0; n0 < 8; ++n0) {
        bf16x8 bfr = Bf[(n0 * 2 + t) * 64 + L];
        acc[n0] = __builtin_amdgcn_mfma_f32_16x16x32_bf16(afr, bfr, acc[n0], 0, 0, 0);
      }
    }
    int rg = L >> 4, cl = L & 15;
#pragma unroll
    for (int half = 0; half < 2; ++half) {
      __syncthreads();
#pragma unroll
      for (int n0 = 0; n0 < 4; ++n0)
#pragma unroll
        for (int r = 0; r < 4; ++r)
          sC[(w * 16 + rg * 4 + r) * 66 + n0 * 16 + cl] = acc[half * 4 + n0][r];
      __syncthreads();
#pragma unroll
      for (int it = 0; it < 2; ++it) {
        int c = tid + it * 256;
        int m = c >> 3, c8 = c & 7;
        int row = m0 + m;
        if (row < NN) {
          float v[8];
#pragma unroll
          for (int j = 0; j < 8; ++j)
            v[j] = sC[m * 66 + c8 * 8 + j] + c1bl[half * 64 + c8 * 8 + j];
          uint4 o;
          o.x = packbf2(v[0], v[1]); o.y = packbf2(v[2], v[3]);
          o.z = packbf2(v[4], v[5]); o.w = packbf2(v[6], v[7]);
          ((uint4*)(ZZ + (size_t)row * 128 + half * 64))[c8] = o;
        }
      }
    }
    return;
  }
  ob -= GB_Z;
  if (ob < GB_CVT) {  // ---- x fp32 -> bf16
    int i = ob * 256 + tid;
    const float4* p = (const float4*)X + (size_t)i * 2;
    float4 a = p[0], c = p[1];
    uint4 o;
    o.x = packbf2(a.x, a.y); o.y = packbf2(a.z, a.w);
    o.z = packbf2(c.x, c.y); o.w = packbf2(c.z, c.w);
    ((uint4*)Xb)[i] = o;
    return;
  }
  ob -= GB_CVT;
  if (ob < GB_BND) {  // ---- graph bounds (sorted batch)
    int g = ob * 256 + tid;
    if (g > NG) return;
    int lo = 0, hi = NN;
    while (lo < hi) {
      int mid = (lo + hi) >> 1;
      if (batch[mid] < g) lo = mid + 1; else hi = mid;
    }
    gstart[g] = lo;
    return;
  }
  ob -= GB_BND;
  if (ob < GB_PREP) {  // ---- pack conv weights (K=128 B-frag layout)
    int yb = ob >> 6, xb = ob & 63;
    const float *WL, *WR; unsigned short* dstp; int N;
    if (yb == 0)      { WL = c1wl; WR = c1wr;           dstp = pL1;  N = 128; }
    else if (yb == 1) { WL = c2wl; WR = c2wl + 64 * 64; dstp = pL2a; N = 64; }
    else if (yb == 2) { WL = c2wr; WR = c2wr + 64 * 64; dstp = pL2b; N = 64; }
    else if (yb == 3) { WL = c3wl; WR = c3wr;           dstp = pL3;  N = 64; }
    else              { WL = c4wl; WR = c4wr;           dstp = pL4;  N = 64; }
    int e = xb * 256 + tid;
    if (e >= 128 * N) return;
    int k = e / N, n = e - k * N;
    float w = (k < 64) ? WL[k * N + n] : WR[(k - 64) * N + n];
    int t = k >> 5, kq = (k >> 3) & 3, j = k & 7;
    int n0 = n >> 4, nl = n & 15;
    dstp[((((n0 * 4 + t) * 64) + (kq * 16 + nl)) << 3) + j] =
        (unsigned short)f2bf1(w);
  }
}

// ----------------- single-pass exclusive scan (decoupled lookback) ----------
// All 391 blocks co-resident (391x256 thr << capacity) -> blockIdx-order
// lookback cannot deadlock. 64-bit device-scope atomics (coherent across
// XCDs): desc = value<<2 | flag (0 empty, 1 aggregate, 2 inclusive-prefix).
__global__ __launch_bounds__(256) void k_scan(const int* __restrict__ cnt,
                                              int* __restrict__ off,
                                              float* __restrict__ inv,
                                              unsigned long long* __restrict__ desc) {
  __shared__ int s[256];
  __shared__ int sbase;
  int b = blockIdx.x, tid = threadIdx.x;
  int i = b * 256 + tid;
  int v = (i < NN) ? cnt[(size_t)i * CPAD] : 0;
  s[tid] = v;
  __syncthreads();
  for (int d = 1; d < 256; d <<= 1) {
    int t = (tid >= d) ? s[tid - d] : 0;
    __syncthreads();
    s[tid] += t;
    __syncthreads();
  }
  if (tid == 0) {
    unsigned long long total = (unsigned long long)s[255];
    atomicExch(&desc[b], (total << 2) | 1ULL);
    long long base = 0;
    int j = b - 1;
    while (j >= 0) {
      unsigned long long d2;
      do { d2 = atomicAdd(&desc[j], 0ULL); } while ((d2 & 3ULL) == 0ULL);
      base += (long long)(d2 >> 2);
      if ((d2 & 3ULL) == 2ULL) break;
      --j;
    }
    atomicExch(&desc[b], (((unsigned long long)(base + (long long)total)) << 2) | 2ULL);
    sbase = (int)base;
  }
  __syncthreads();
  if (i < NN) {
    off[i] = sbase + s[tid] - v;  // exclusive global prefix
    inv[i] = 1.0f / fmaxf((float)v, 1.0f);
  }
  if (i == 0) off[NN] = NE;
}

// ------------------------------------------------------------------- fill ---
__global__ __launch_bounds__(256) void k_fill(const int* __restrict__ src,
                                              const int* __restrict__ dst,
                                              const int* __restrict__ off,
                                              const int* __restrict__ rank,
                                              int* __restrict__ csr) {
  int e = blockIdx.x * 256 + threadIdx.x;
  if (e < NE) csr[off[dst[e]] + rank[e]] = src[e];
}

// ---------------------------- gather (layer-2 epilogue: relu(agg+b+Z)) ------
__global__ __launch_bounds__(256) void k_gather(
    const unsigned short* __restrict__ F, const int* __restrict__ csr,
    const int* __restrict__ off, const float* __restrict__ inv,
    const float* __restrict__ bias, const unsigned short* __restrict__ Z,
    unsigned short* __restrict__ out) {
  int idx = blockIdx.x * 256 + threadIdx.x;  // grid = NN*8 threads
  int n = idx >> 3, q = idx & 7;
  int beg = off[n], end = off[n + 1];
  float aA[8], aB[8];
#pragma unroll
  for (int c = 0; c < 8; ++c) { aA[c] = 0.f; aB[c] = 0.f; }
  int e = beg;
  for (; e + 4 <= end; e += 4) {
    uint4 v[4];
#pragma unroll
    for (int j = 0; j < 4; ++j)
      v[j] = ((const uint4*)(F + (size_t)csr[e + j] * 64))[q];
#pragma unroll
    for (int j = 0; j < 4; j += 2) {
      aA[0] += bflo(v[j].x); aB[0] += bflo(v[j + 1].x);
      aA[1] += bfhi(v[j].x); aB[1] += bfhi(v[j + 1].x);
      aA[2] += bflo(v[j].y); aB[2] += bflo(v[j + 1].y);
      aA[3] += bfhi(v[j].y); aB[3] += bfhi(v[j + 1].y);
      aA[4] += bflo(v[j].z); aB[4] += bflo(v[j + 1].z);
      aA[5] += bfhi(v[j].z); aB[5] += bfhi(v[j + 1].z);
      aA[6] += bflo(v[j].w); aB[6] += bflo(v[j + 1].w);
      aA[7] += bfhi(v[j].w); aB[7] += bfhi(v[j + 1].w);
    }
  }
  for (; e < end; ++e) {
    uint4 v0 = ((const uint4*)(F + (size_t)csr[e] * 64))[q];
    aA[0] += bflo(v0.x); aA[1] += bfhi(v0.x);
    aA[2] += bflo(v0.y); aA[3] += bfhi(v0.y);
    aA[4] += bflo(v0.z); aA[5] += bfhi(v0.z);
    aA[6] += bflo(v0.w); aA[7] += bfhi(v0.w);
  }
  float a[8];
  float iv = inv[n];
#pragma unroll
  for (int c = 0; c < 8; ++c) a[c] = (aA[c] + aB[c]) * iv;
  {
    uint4 z = ((const uint4*)(Z + (size_t)n * 64))[q];
    const float4* bp = (const float4*)(bias + q * 8);
    float4 b0 = bp[0], b1 = bp[1];
    a[0] = fmaxf(a[0] + b0.x + bflo(z.x), 0.f);
    a[1] = fmaxf(a[1] + b0.y + bfhi(z.x), 0.f);
    a[2] = fmaxf(a[2] + b0.z + bflo(z.y), 0.f);
    a[3] = fmaxf(a[3] + b0.w + bfhi(z.y), 0.f);
    a[4] = fmaxf(a[4] + b1.x + bflo(z.z), 0.f);
    a[5] = fmaxf(a[5] + b1.y + bfhi(z.z), 0.f);
    a[6] = fmaxf(a[6] + b1.z + bflo(z.w), 0.f);
    a[7] = fmaxf(a[7] + b1.w + bfhi(z.w), 0.f);
  }
  uint4 o;
  o.x = packbf2(a[0], a[1]); o.y = packbf2(a[2], a[3]);
  o.z = packbf2(a[4], a[5]); o.w = packbf2(a[6], a[7]);
  ((uint4*)(out + (size_t)n * 64))[q] = o;
}

// -------------------- layer-1 fused: h1 = relu(agg(x)@WL + Z)  (K=64) -------
__global__ __launch_bounds__(256, 4) void k_fgemm1(
    const unsigned short* __restrict__ F, const int* __restrict__ csr,
    const int* __restrict__ off, const float* __restrict__ inv,
    const unsigned short* __restrict__ Wp,   // pL1 (K=128 layout; WL = t 0,1)
    const unsigned short* __restrict__ ZZ,   // NN x 128 (x@wr + bias)
    unsigned short* __restrict__ OUT) {
  __shared__ __align__(16) char smem[64 * 66 * 4];
  unsigned short* sA = (unsigned short*)smem;
  float* sC = (float*)smem;
  const int tid = threadIdx.x;
  const int m0 = blockIdx.x * 64;

  {
    int m = tid >> 2, qr = tid & 3;
    int row = m0 + m;
    float a0[16], a1[16];
#pragma unroll
    for (int c = 0; c < 16; ++c) { a0[c] = 0.f; a1[c] = 0.f; }
    if (row < NN) {
      int beg = off[row], end = off[row + 1];
      int e = beg;
      for (; e + 2 <= end; e += 2) {
        int s0 = csr[e], s1 = csr[e + 1];
        const uint4* r0 = (const uint4*)(F + (size_t)s0 * 64) + qr * 2;
        const uint4* r1 = (const uint4*)(F + (size_t)s1 * 64) + qr * 2;
        uint4 p0 = r0[0], p1 = r0[1], q0 = r1[0], q1 = r1[1];
        a0[0] += bflo(p0.x); a0[1] += bfhi(p0.x);
        a0[2] += bflo(p0.y); a0[3] += bfhi(p0.y);
        a0[4] += bflo(p0.z); a0[5] += bfhi(p0.z);
        a0[6] += bflo(p0.w); a0[7] += bfhi(p0.w);
        a0[8] += bflo(p1.x); a0[9] += bfhi(p1.x);
        a0[10] += bflo(p1.y); a0[11] += bfhi(p1.y);
        a0[12] += bflo(p1.z); a0[13] += bfhi(p1.z);
        a0[14] += bflo(p1.w); a0[15] += bfhi(p1.w);
        a1[0] += bflo(q0.x); a1[1] += bfhi(q0.x);
        a1[2] += bflo(q0.y); a1[3] += bfhi(q0.y);
        a1[4] += bflo(q0.z); a1[5] += bfhi(q0.z);
        a1[6] += bflo(q0.w); a1[7] += bfhi(q0.w);
        a1[8] += bflo(q1.x); a1[9] += bfhi(q1.x);
        a1[10] += bflo(q1.y); a1[11] += bfhi(q1.y);
        a1[12] += bflo(q1.z); a1[13] += bfhi(q1.z);
        a1[14] += bflo(q1.w); a1[15] += bfhi(q1.w);
      }
      if (e < end) {
        const uint4* r0 = (const uint4*)(F + (size_t)csr[e] * 64) + qr * 2;
        uint4 p0 = r0[0], p1 = r0[1];
        a0[0] += bflo(p0.x); a0[1] += bfhi(p0.x);
        a0[2] += bflo(p0.y); a0[3] += bfhi(p0.y);
        a0[4] += bflo(p0.z); a0[5] += bfhi(p0.z);
        a0[6] += bflo(p0.w); a0[7] += bfhi(p0.w);
        a0[8] += bflo(p1.x); a0[9] += bfhi(p1.x);
        a0[10] += bflo(p1.y); a0[11] += bfhi(p1.y);
        a0[12] += bflo(p1.z); a0[13] += bfhi(p1.z);
        a0[14] += bflo(p1.w); a0[15] += bfhi(p1.w);
      }
      float iv = inv[row];
#pragma unroll
      for (int c = 0; c < 16; ++c) a0[c] = (a0[c] + a1[c]) * iv;
    }
    int wv = m >> 4, mr = m & 15;
#pragma unroll
    for (int h = 0; h < 2; ++h) {
      int k8 = qr * 2 + h;
      int t = k8 >> 2, kq = k8 & 3;
      uint4 o;
      o.x = packbf2(a0[h * 8 + 0], a0[h * 8 + 1]);
      o.y = packbf2(a0[h * 8 + 2], a0[h * 8 + 3]);
      o.z = packbf2(a0[h * 8 + 4], a0[h * 8 + 5]);
      o.w = packbf2(a0[h * 8 + 6], a0[h * 8 + 7]);
      ((uint4*)sA)[(wv * 2 + t) * 64 + kq * 16 + mr] = o;
    }
  }
  __syncthreads();

  const int w = tid >> 6, L = tid & 63;
  const bf16x8* Af = (const bf16x8*)sA;
  const bf16x8* Bf = (const bf16x8*)Wp;
  f32x4 acc[8];
#pragma unroll
  for (int i = 0; i < 8; ++i)
#pragma unroll
    for (int j = 0; j < 4; ++j) acc[i][j] = 0.f;
#pragma unroll
  for (int t = 0; t < 2; ++t) {
    bf16x8 afr = Af[(w * 2 + t) * 64 + L];
#pragma unroll
    for (int n0 = 0; n0 < 8; ++n0) {
      bf16x8 bfr = Bf[(n0 * 4 + t) * 64 + L];
      acc[n0] = __builtin_amdgcn_mfma_f32_16x16x32_bf16(afr, bfr, acc[n0], 0, 0, 0);
    }
  }

  int rg = L >> 4, cl = L & 15;
#pragma unroll
  for (int half = 0; half < 2; ++half) {
    __syncthreads();
#pragma unroll
    for (int n0 = 0; n0 < 4; ++n0)
#pragma unroll
      for (int r = 0; r < 4; ++r)
        sC[(w * 16 + rg * 4 + r) * 66 + n0 * 16 + cl] = acc[half * 4 + n0][r];
    __syncthreads();
#pragma unroll
    for (int it = 0; it < 2; ++it) {
      int c = tid + it * 256;
      int m = c >> 3, c8 = c & 7;
      int row = m0 + m;
      if (row < NN) {
        uint4 z = ((const uint4*)(ZZ + (size_t)row * 128 + half * 64))[c8];
        float zb[8] = {bflo(z.x), bfhi(z.x), bflo(z.y), bfhi(z.y),
                       bflo(z.z), bfhi(z.z), bflo(z.w), bfhi(z.w)};
        float v[8];
#pragma unroll
        for (int j = 0; j < 8; ++j)
          v[j] = fmaxf(sC[m * 66 + c8 * 8 + j] + zb[j], 0.f);
        uint4 o;
        o.x = packbf2(v[0], v[1]); o.y = packbf2(v[2], v[3]);
        o.z = packbf2(v[4], v[5]); o.w = packbf2(v[6], v[7]);
        ((uint4*)(OUT + (size_t)row * 128 + half * 64))[c8] = o;
      }
    }
  }
}

// ------------------------------------------- fused gather + MFMA GEMM -------
template <int NF>
__global__ __launch_bounds__(256, 4) void k_fgemm(
    const unsigned short* __restrict__ F, const int* __restrict__ csr,
    const int* __restrict__ off, const float* __restrict__ inv,
    const unsigned short* __restrict__ Wp, const float* __restrict__ bias,
    unsigned short* __restrict__ OUT, int outStride) {
  __shared__ __align__(16) char smem[64 * 66 * 4];
  unsigned short* sA = (unsigned short*)smem;
  float* sC = (float*)smem;
  const int tid = threadIdx.x;
  const int m0 = blockIdx.x * 64;

  {
    int m = tid >> 2, qr = tid & 3;
    int row = m0 + m;
    float a0[16], a1[16];
#pragma unroll
    for (int c = 0; c < 16; ++c) { a0[c] = 0.f; a1[c] = 0.f; }
    if (row < NN) {
      int beg = off[row], end = off[row + 1];
      int e = beg;
      for (; e + 2 <= end; e += 2) {
        int s0 = csr[e], s1 = csr[e + 1];
        const uint4* r0 = (const uint4*)(F + (size_t)s0 * 64) + qr * 2;
        const uint4* r1 = (const uint4*)(F + (size_t)s1 * 64) + qr * 2;
        uint4 p0 = r0[0], p1 = r0[1], q0 = r1[0], q1 = r1[1];
        a0[0] += bflo(p0.x); a0[1] += bfhi(p0.x);
        a0[2] += bflo(p0.y); a0[3] += bfhi(p0.y);
        a0[4] += bflo(p0.z); a0[5] += bfhi(p0.z);
        a0[6] += bflo(p0.w); a0[7] += bfhi(p0.w);
        a0[8] += bflo(p1.x); a0[9] += bfhi(p1.x);
        a0[10] += bflo(p1.y); a0[11] += bfhi(p1.y);
        a0[12] += bflo(p1.z); a0[13] += bfhi(p1.z);
        a0[14] += bflo(p1.w); a0[15] += bfhi(p1.w);
        a1[0] += bflo(q0.x); a1[1] += bfhi(q0.x);
        a1[2] += bflo(q0.y); a1[3] += bfhi(q0.y);
        a1[4] += bflo(q0.z); a1[5] += bfhi(q0.z);
        a1[6] += bflo(q0.w); a1[7] += bfhi(q0.w);
        a1[8] += bflo(q1.x); a1[9] += bfhi(q1.x);
        a1[10] += bflo(q1.y); a1[11] += bfhi(q1.y);
        a1[12] += bflo(q1.z); a1[13] += bfhi(q1.z);
        a1[14] += bflo(q1.w); a1[15] += bfhi(q1.w);
      }
      if (e < end) {
        const uint4* r0 = (const uint4*)(F + (size_t)csr[e] * 64) + qr * 2;
        uint4 p0 = r0[0], p1 = r0[1];
        a0[0] += bflo(p0.x); a0[1] += bfhi(p0.x);
        a0[2] += bflo(p0.y); a0[3] += bfhi(p0.y);
        a0[4] += bflo(p0.z); a0[5] += bfhi(p0.z);
        a0[6] += bflo(p0.w); a0[7] += bfhi(p0.w);
        a0[8] += bflo(p1.x); a0[9] += bfhi(p1.x);
        a0[10] += bflo(p1.y); a0[11] += bfhi(p1.y);
        a0[12] += bflo(p1.z); a0[13] += bfhi(p1.z);
        a0[14] += bflo(p1.w); a0[15] += bfhi(p1.w);
      }
      float iv = inv[row];
#pragma unroll
      for (int c = 0; c < 16; ++c) a0[c] = (a0[c] + a1[c]) * iv;
    }
    int wv = m >> 4, mr = m & 15;
#pragma unroll
    for (int h = 0; h < 2; ++h) {
      int k8 = qr * 2 + h;
      int t = k8 >> 2, kq = k8 & 3;
      uint4 o;
      o.x = packbf2(a0[h * 8 + 0], a0[h * 8 + 1]);
      o.y = packbf2(a0[h * 8 + 2], a0[h * 8 + 3]);
      o.z = packbf2(a0[h * 8 + 4], a0[h * 8 + 5]);
      o.w = packbf2(a0[h * 8 + 6], a0[h * 8 + 7]);
      ((uint4*)sA)[(wv * 4 + t) * 64 + kq * 16 + mr] = o;
    }
  }
#pragma unroll
  for (int l = 0; l < 2; ++l) {
    int c = tid + l * 256;
    int m = c >> 3, j = c & 7;
    int row = m0 + m;
    uint4 v = make_uint4(0, 0, 0, 0);
    if (row < NN) v = ((const uint4*)(F + (size_t)row * 64))[j];
    int k8 = 8 + j, t = k8 >> 2, kq = k8 & 3;
    int wv = m >> 4, mr = m & 15;
    ((uint4*)sA)[(wv * 4 + t) * 64 + kq * 16 + mr] = v;
  }
  __syncthreads();

  const int w = tid >> 6, L = tid & 63;
  const bf16x8* Af = (const bf16x8*)sA;
  const bf16x8* Bf = (const bf16x8*)Wp;
  f32x4 acc[NF];
#pragma unroll
  for (int i = 0; i < NF; ++i)
#pragma unroll
    for (int j = 0; j < 4; ++j) acc[i][j] = 0.f;
#pragma unroll
  for (int t = 0; t < 4; ++t) {
    bf16x8 afr = Af[(w * 4 + t) * 64 + L];
#pragma unroll
    for (int n0 = 0; n0 < NF; ++n0) {
      bf16x8 bfr = Bf[(n0 * 4 + t) * 64 + L];
      acc[n0] = __builtin_amdgcn_mfma_f32_16x16x32_bf16(afr, bfr, acc[n0], 0, 0, 0);
    }
  }

  int rg = L >> 4, cl = L & 15;
#pragma unroll
  for (int half = 0; half < NF / 4; ++half) {
    __syncthreads();
#pragma unroll
    for (int n0 = 0; n0 < 4; ++n0)
#pragma unroll
      for (int r = 0; r < 4; ++r)
        sC[(w * 16 + rg * 4 + r) * 66 + n0 * 16 + cl] = acc[half * 4 + n0][r];
    __syncthreads();
#pragma unroll
    for (int it = 0; it < 2; ++it) {
      int c = tid + it * 256;
      int m = c >> 3, c8 = c & 7;
      int row = m0 + m;
      if (row < NN) {
        float v[8];
#pragma unroll
        for (int j = 0; j < 8; ++j)
          v[j] = fmaxf(sC[m * 66 + c8 * 8 + j] + bias[half * 64 + c8 * 8 + j], 0.f);
        uint4 o;
        o.x = packbf2(v[0], v[1]); o.y = packbf2(v[2], v[3]);
        o.z = packbf2(v[4], v[5]); o.w = packbf2(v[6], v[7]);
        ((uint4*)(OUT + (size_t)row * outStride + half * 64))[c8] = o;
      }
    }
  }
}

// ------------------------------------------------------------ MFMA GEMM -----
// (layer 2: h1 @ wl -> OUT, h1 @ wr -> OUT2)
__global__ __launch_bounds__(256) void k_gemm(
    const unsigned short* __restrict__ S0,
    const unsigned short* __restrict__ Wp,
    const unsigned short* __restrict__ Wp2, unsigned short* __restrict__ OUT2,
    unsigned short* __restrict__ OUT, int M) {
  __shared__ __align__(16) char smem[64 * 66 * 4];
  unsigned short* sA = (unsigned short*)smem;
  float* sC = (float*)smem;
  const int tid = threadIdx.x;
  if (blockIdx.y == 1) { Wp = Wp2; OUT = OUT2; }
  const int m0 = blockIdx.x * 64;

#pragma unroll
  for (int l = 0; l < 4; ++l) {
    int c = tid + l * 256;
    int m = c >> 4, k8 = c & 15;
    int row = m0 + m;
    uint4 v = make_uint4(0, 0, 0, 0);
    if (row < M) v = ((const uint4*)(S0 + (size_t)row * 128))[k8];
    int wv = m >> 4, mr = m & 15, t = k8 >> 2, kq = k8 & 3;
    ((uint4*)sA)[(wv * 4 + t) * 64 + (kq * 16 + mr)] = v;
  }
  __syncthreads();

  const int w = tid >> 6, L = tid & 63;
  f32x4 acc[4];
#pragma unroll
  for (int i = 0; i < 4; ++i)
#pragma unroll
    for (int j = 0; j < 4; ++j) acc[i][j] = 0.f;

  const bf16x8* Af = (const bf16x8*)sA;
  const bf16x8* Bf = (const bf16x8*)Wp;
#pragma unroll
  for (int t = 0; t < 4; ++t) {
    bf16x8 afr = Af[(w * 4 + t) * 64 + L];
#pragma unroll
    for (int n0 = 0; n0 < 4; ++n0) {
      bf16x8 bfr = Bf[(n0 * 4 + t) * 64 + L];
      acc[n0] = __builtin_amdgcn_mfma_f32_16x16x32_bf16(afr, bfr, acc[n0], 0, 0, 0);
    }
  }
  __syncthreads();
  {
    int rg = L >> 4, cl = L & 15;
#pragma unroll
    for (int n0 = 0; n0 < 4; ++n0)
#pragma unroll
      for (int r = 0; r < 4; ++r)
        sC[(w * 16 + rg * 4 + r) * 66 + n0 * 16 + cl] = acc[n0][r];
  }
  __syncthreads();
#pragma unroll
  for (int it = 0; it < 2; ++it) {
    int c = tid + it * 256;
    int m = c >> 3, c8 = c & 7;
    int row = m0 + m;
    if (row < M) {
      float v[8];
#pragma unroll
      for (int j = 0; j < 8; ++j) v[j] = sC[m * 66 + c8 * 8 + j];
      uint4 o;
      o.x = packbf2(v[0], v[1]); o.y = packbf2(v[2], v[3]);
      o.z = packbf2(v[4], v[5]); o.w = packbf2(v[6], v[7]);
      ((uint4*)(OUT + (size_t)row * 64))[c8] = o;
    }
  }
}

// ----------------------------------------------- fused mean-pool + MLP ------
__global__ __launch_bounds__(64) void k_poolmlp(
    const unsigned short* __restrict__ H, const int* __restrict__ gstart,
    const float* __restrict__ w1, const float* __restrict__ b1,
    const float* __restrict__ w2, const float* __restrict__ b2,
    const float* __restrict__ w3, const float* __restrict__ b3,
    const float* __restrict__ w4, const float* __restrict__ b4,
    float* __restrict__ out) {
  __shared__ float sg[64], s1[64], s2[32], s3[32];
  int g = blockIdx.x, t = threadIdx.x;
  int beg = gstart[g], end = gstart[g + 1];
  float acc = 0.0f;
#pragma unroll 4
  for (int n = beg; n < end; ++n) acc += bfs(H[(size_t)n * 64 + t]);
  float cnt = fmaxf((float)(end - beg), 1.0f);
  sg[t] = acc / cnt;
  __syncthreads();
  acc = b1[t];
  for (int k = 0; k < 64; ++k) acc += sg[k] * w1[k * 64 + t];
  s1[t] = fmaxf(acc, 0.0f);
  __syncthreads();
  if (t < 32) {
    acc = b2[t];
    for (int k = 0; k < 64; ++k) acc += s1[k] * w2[k * 32 + t];
    s2[t] = fmaxf(acc, 0.0f);
  }
  __syncthreads();
  if (t < 32) {
    acc = b3[t];
    for (int k = 0; k < 32; ++k) acc += s2[k] * w3[k * 32 + t];
    s3[t] = fmaxf(acc, 0.0f);
  }
  __syncthreads();
  if (t == 0) {
    acc = b4[0];
    for (int k = 0; k < 32; ++k) acc += s3[k] * w4[k];
    out[g] = acc;
  }
}

// ---------------------------------------------------------------- launch ----
extern "C" void kernel_launch(void* const* d_in, const int* in_sizes, int n_in,
                              void* d_out, int out_size, void* d_ws,
                              size_t ws_size, hipStream_t stream) {
  const float* x     = (const float*)d_in[0];
  const int*   ei    = (const int*)d_in[1];
  const int*   batch = (const int*)d_in[2];
  const int* src = ei;
  const int* dst = ei + NE;

  const float* c1_wl = (const float*)d_in[3];
  const float* c1_bl = (const float*)d_in[4];
  const float* c1_wr = (const float*)d_in[5];
  const float* c2_wl = (const float*)d_in[6];
  const float* c2_bl = (const float*)d_in[7];
  const float* c2_wr = (const float*)d_in[8];
  const float* c3_wl = (const float*)d_in[9];
  const float* c3_bl = (const float*)d_in[10];
  const float* c3_wr = (const float*)d_in[11];
  const float* c4_wl = (const float*)d_in[12];
  const float* c4_bl = (const float*)d_in[13];
  const float* c4_wr = (const float*)d_in[14];
  const float* l1w = (const float*)d_in[15];
  const float* l1b = (const float*)d_in[16];
  const float* l2w = (const float*)d_in[17];
  const float* l2b = (const float*)d_in[18];
  const float* l3w = (const float*)d_in[19];
  const float* l3b = (const float*)d_in[20];
  const float* l4w = (const float*)d_in[21];
  const float* l4b = (const float*)d_in[22];

  // ---- workspace carve-up
  char* wsb = (char*)d_ws;
  float* inv = (float*)wsb;                                   // NN fp32
  unsigned short* xb  = (unsigned short*)(wsb + (size_t)NN * 4);
  unsigned short* B1  = xb + (size_t)NN * 64;    // h2 / h4
  unsigned short* B2  = B1 + (size_t)NN * 64;    // h1 (NN x 128)
  unsigned short* B3  = B2 + (size_t)NN * 128;   // U / h3
  unsigned short* B4  = B3 + (size_t)NN * 64;    // V
  unsigned short* ZZ  = B4 + (size_t)NN * 64;    // x@wr + bias (NN x 128)
  unsigned short* pL1  = ZZ + (size_t)NN * 128;
  unsigned short* pL2a = pL1 + 128 * 128;
  unsigned short* pL2b = pL2a + 128 * 64;
  unsigned short* pL3  = pL2b + 128 * 64;
  unsigned short* pL4  = pL3 + 128 * 64;
  unsigned short* pLZ  = pL4 + 128 * 64;
  int* cnt    = (int*)(pLZ + 64 * 128);          // NN*CPAD
  int* off    = cnt + (size_t)NN * CPAD;         // NN+1
  int* gstart = off + NN + 1;                    // NG+1
  int* csr    = gstart + NG + 1 + 2;             // NE
  int* rank   = csr + NE;                        // NE
  unsigned long long* desc =
      (unsigned long long*)(((uintptr_t)(rank + NE) + 15) & ~(uintptr_t)15);  // 512

  const int gE  = (NE + 255) / 256;   // 6250
  const int gN8 = NN * 8 / 256;       // 3125
  const int gM  = (NN + 63) / 64;     // 1563
  const int gN  = NBLK_SCAN;          // 391

  // ---- prep0: pLZ pack + cnt/desc zero (replaces memset + prepz)
  k_prep0<<<GB_P0, 256, 0, stream>>>(c1_wr, pLZ, cnt, desc);

  // ---- merged setup: count interleaved 1:1 with Z-gemm/cvt/bounds/prep
  k_setup<<<GB_SETUP, 256, 0, stream>>>(dst, cnt, rank, x, xb, batch, gstart,
                                        pLZ, c1_bl, ZZ,
                                        c1_wl, c1_wr, c2_wl, c2_wr,
                                        c3_wl, c3_wr, c4_wl, c4_wr,
                                        pL1, pL2a, pL2b, pL3, pL4);
  // ---- single-pass scan (decoupled lookback) + invdeg
  k_scan<<<gN, 256, 0, stream>>>(cnt, off, inv, desc);
  k_fill<<<gE, 256, 0, stream>>>(src, dst, off, rank, csr);

  // ---- layer 1 (fused, K=64): B2(h1) = relu(agg(x)@WL + ZZ)
  k_fgemm1<<<gM, 256, 0, stream>>>(xb, csr, off, inv, pL1, ZZ, B2);

  // ---- layer 2: B3 = h1@wl, B4 = h1@wr; B1(h2) = relu(agg(B3) + b + B4)
  k_gemm<<<dim3(gM, 2), 256, 0, stream>>>(B2, pL2a, pL2b, B4, B3, NN);
  k_gather<<<gN8, 256, 0, stream>>>(B3, csr, off, inv, c2_bl, B4, B1);

  // ---- layer 3 (fused): B3(h3) = relu([agg(h2)|h2] @ pL3 + c3_bl)
  k_fgemm<4><<<gM, 256, 0, stream>>>(B1, csr, off, inv, pL3, c3_bl, B3, 64);

  // ---- layer 4 (fused): B1(h4) = relu([agg(h3)|h3] @ pL4 + c4_bl)
  k_fgemm<4><<<gM, 256, 0, stream>>>(B3, csr, off, inv, pL4, c4_bl, B1, 64);

  // ---- fused pool + MLP
  k_poolmlp<<<NG, 64, 0, stream>>>(B1, gstart, l1w, l1b, l2w, l2b,
                                   l3w, l3b, l4w, l4b, (float*)d_out);
}